// Round 10
// baseline (941.502 us; speedup 1.0000x reference)
//
#include <hip/hip_runtime.h>
#include <hip/hip_bf16.h>

// MoE top-2-of-8 FFN + shared expert + router losses, MI355X gfx950.
// R8: m97-canonical 128^2 single-buffer GEMM, 4 blocks/CU (926us best).
// R9-R12 lessons: (256,5) spills (body needs 128 unified regs = 4/CU cliff);
//     BN=64 and BM=256 variants both lower the per-CU rate; per-CU rate
//     ~1.31 GF/us only at 128^2 tile with >=4-deep block TLP.
// R13: sv+ev merge was a wash (267 vs 258): same round count, and sub-4-deep
//     rounds run slower. sv measured ~48us (near-ideal); ev = 105 (full
//     round) + 105 (64-block idle round).
// R14: kill ev's idle round by BACKFILLING with sk (the only dependency-legal
//     pairing): order ek -> merged[ev + sk] -> sv.
//     - merged grid 3136: ids 0..1087 = ev items (T~105, long, launch first);
//       ids 1088..3135 = sk items (T~26, backfill the tail).
//     - busy = 1088*105 + 2048*26 ~ 167.5k block-us / 1024 slots ~ 164us
//       vs 52 + 210 = 262 separate.
//     - both branches are the byte-identical R8 body (block-uniform branch).
//     - wt 9 slots; sv_w^T transposed into slot 8 AFTER merged (sk done).

#define N_TOK 8192
#define DM    1024
#define HD    4096
#define NE    8
#define NKTOT 16384            // N_TOK * 2
#define PERM_CAP 17408         // NKTOT + NE*128 (segment padding)
#define MAX_TILES 136          // sum ceil(T_e/128) <= NKTOT/128 + NE
#define BAND 17                // MAX_TILES / 8 xcds
#define EV_BLOCKS 1088         // 8 xcd * 17 m * 8 n
#define RTOK_BLK 16            // router tokens per block

typedef __attribute__((ext_vector_type(8))) short bhalf8;
typedef __attribute__((ext_vector_type(8))) unsigned short ushort8v;
typedef __attribute__((ext_vector_type(4))) float floatx4;

__device__ __forceinline__ unsigned short f2bf(float f) {
  union { float f; unsigned int u; } v; v.f = f;
  unsigned int u = v.u;
  return (unsigned short)((u + 0x7fffu + ((u >> 16) & 1u)) >> 16);  // RNE
}

__device__ __forceinline__ float bf2f(unsigned short h) {
  union { unsigned int u; float f; } v; v.u = ((unsigned int)h) << 16;
  return v.f;
}

__device__ __forceinline__ float gelu_tanh(float h) {
  // jax.nn.gelu default (approximate=True)
  float u = 0.7978845608028654f * (h + 0.044715f * h * h * h);
  float t = 1.0f - 2.0f / (1.0f + __expf(2.0f * u));   // tanh(u)
  return 0.5f * h * (1.0f + t);
}

// global -> LDS direct DMA, 16B/lane. LDS dest is wave-uniform base + lane*16.
__device__ __forceinline__ void gload16(const unsigned short* g, void* l) {
  __builtin_amdgcn_global_load_lds(
      (const __attribute__((address_space(1))) void*)g,
      (__attribute__((address_space(3))) void*)l, 16, 0, 0);
}

// ---------------- init (ws is poisoned 0xAA each call) ----------------
__global__ void init_kernel(int* perm, float* permw, float* usage, float* zsum,
                            int* counts, int* fill) {
  int i = blockIdx.x * 256 + threadIdx.x;
  if (i < PERM_CAP) { perm[i] = 0; permw[i] = 0.0f; }
  if (i < NE) { usage[i] = 0.0f; counts[i] = 0; fill[i] = 0; }
  if (i == 0) zsum[0] = 0.0f;
}

// ---------------- x fp32 -> bf16 ----------------
__global__ void cvt_x_kernel(const float* __restrict__ x, unsigned short* __restrict__ xb) {
  size_t i = (size_t)(blockIdx.x * 256 + threadIdx.x) * 4;
  float4 v = *(const float4*)(x + i);
  ushort4 o;
  o.x = f2bf(v.x); o.y = f2bf(v.y); o.z = f2bf(v.z); o.w = f2bf(v.w);
  *(ushort4*)(xb + i) = o;
}

// ---------------- router: logits, top-2 softmax, aux-loss partials ----------------
__global__ void router_kernel(const float* __restrict__ x, const float* __restrict__ gw,
                              int* __restrict__ idxb, float* __restrict__ wbuf,
                              float* __restrict__ usage, float* __restrict__ zsum,
                              int* __restrict__ counts) {
  __shared__ float s_use[NE];
  __shared__ int   s_cnt[NE];
  __shared__ float s_z;
  int t = threadIdx.x;
  if (t < NE) { s_use[t] = 0.0f; s_cnt[t] = 0; }
  if (t == 0) s_z = 0.0f;
  __syncthreads();

  int wave = t >> 6;
  int lane = t & 63;

  float luse[NE]; int lcnt[NE];
#pragma unroll
  for (int e = 0; e < NE; e++) { luse[e] = 0.0f; lcnt[e] = 0; }
  float lz = 0.0f;

#pragma unroll
  for (int i = 0; i < 4; i++) {
    int n = blockIdx.x * RTOK_BLK + wave * 4 + i;
    const float* xr = x + (size_t)n * DM;
    float acc[NE];
#pragma unroll
    for (int e = 0; e < NE; e++) acc[e] = 0.0f;
    for (int d = lane; d < DM; d += 64) {
      float xv = xr[d];
      const float* g = gw + (size_t)d * NE;
#pragma unroll
      for (int e = 0; e < NE; e++) acc[e] += xv * g[e];
    }
#pragma unroll
    for (int e = 0; e < NE; e++) {
#pragma unroll
      for (int off = 32; off > 0; off >>= 1) acc[e] += __shfl_xor(acc[e], off);
    }
    if (lane == 0) {
      float m1 = acc[0]; int i1 = 0;
#pragma unroll
      for (int e = 1; e < NE; e++) if (acc[e] > m1) { m1 = acc[e]; i1 = e; }
      float m2 = -3.0e38f; int i2 = 0;
#pragma unroll
      for (int e = 0; e < NE; e++) if (e != i1 && acc[e] > m2) { m2 = acc[e]; i2 = e; }
      float e1 = __expf(m2 - m1);
      float w1 = 1.0f / (1.0f + e1);
      float w2 = e1 / (1.0f + e1);
      float s = 0.0f;
#pragma unroll
      for (int e = 0; e < NE; e++) s += __expf(acc[e] - m1);
      float lse = m1 + __logf(s);
      idxb[n * 2 + 0] = i1; idxb[n * 2 + 1] = i2;
      wbuf[n * 2 + 0] = w1; wbuf[n * 2 + 1] = w2;
      luse[i1] += w1; luse[i2] += w2;
      lcnt[i1]++;     lcnt[i2]++;
      lz += lse * lse;
    }
  }

  if (lane == 0) {
#pragma unroll
    for (int e = 0; e < NE; e++) {
      atomicAdd(&s_use[e], luse[e]);
      atomicAdd(&s_cnt[e], lcnt[e]);
    }
    atomicAdd(&s_z, lz);
  }
  __syncthreads();
  if (t < NE) {
    atomicAdd(&usage[t], s_use[t]);
    atomicAdd(&counts[t], s_cnt[t]);
  }
  if (t == 0) atomicAdd(zsum, s_z);
}

// ---------------- scan: padded segment offsets, tile table, router loss ----------------
__global__ void scan_kernel(const int* __restrict__ counts, int* __restrict__ poff,
                            int* __restrict__ tileE, int* __restrict__ tileR,
                            int* __restrict__ nTiles,
                            const float* __restrict__ usage, const float* __restrict__ zsum,
                            float* __restrict__ lossOut) {
  if (threadIdx.x == 0 && blockIdx.x == 0) {
    int run = 0, nt = 0;
    for (int e = 0; e < NE; e++) {
      poff[e] = run;
      int t = (counts[e] + 127) >> 7;
      for (int i = 0; i < t; i++) { tileE[nt] = e; tileR[nt] = run + i * 128; nt++; }
      run += t << 7;
    }
    *nTiles = nt;
    float mean = 0.0f;
    for (int e = 0; e < NE; e++) mean += usage[e];
    mean *= (1.0f / NE);
    float var = 0.0f;
    for (int e = 0; e < NE; e++) { float d = usage[e] - mean; var += d * d; }
    var *= (1.0f / NE);
    float bal = sqrtf(var) / mean * 0.01f;
    float z = (zsum[0] / (float)N_TOK) * 0.001f;
    lossOut[0] = bal + z;
  }
}

// ---------------- scatter tokens into per-expert segments ----------------
__global__ void scatter_kernel(const int* __restrict__ idxb, const float* __restrict__ wbuf,
                               const int* __restrict__ poff, int* __restrict__ fill,
                               int* __restrict__ perm, float* __restrict__ permw,
                               int* __restrict__ pos) {
  __shared__ int lcnt[NE];
  __shared__ int lbase[NE];
  int t = threadIdx.x;
  if (t < NE) lcnt[t] = 0;
  __syncthreads();
  int i = blockIdx.x * 256 + t;          // grid sized exactly: i < NKTOT
  int e = idxb[i];
  int r = atomicAdd(&lcnt[e], 1);        // LDS rank within block
  __syncthreads();
  if (t < NE) lbase[t] = atomicAdd(&fill[t], lcnt[t]);
  __syncthreads();
  int p = poff[e] + lbase[e] + r;
  perm[p] = i >> 1;
  permw[p] = wbuf[i];
  pos[i] = p;
}

// ---------------- transpose+convert: src fp32 [R][C] -> dst bf16 [C][R], batched ----------------
// dst writes vectorized: each lane stores ushort8 (16B). LDS read stride 65
// words -> 2-way bank aliasing only (free).
__global__ void transpose_cvt_kernel(const float* __restrict__ src,
                                     unsigned short* __restrict__ dst, int R, int C) {
  __shared__ float tile[64][65];
  size_t bo = (size_t)blockIdx.z * R * C;
  src += bo; dst += bo;
  int r0 = blockIdx.x * 64, c0 = blockIdx.y * 64;
  int c = threadIdx.x & 63, r = threadIdx.x >> 6;
#pragma unroll
  for (int i = 0; i < 16; i++)
    tile[r + i * 4][c] = src[(size_t)(r0 + r + i * 4) * C + c0 + c];
  __syncthreads();
  int u = threadIdx.x & 7;        // dst 8-col group (src row group)
  int ow = threadIdx.x >> 3;      // 0..31: dst row offset base
#pragma unroll
  for (int it = 0; it < 2; it++) {
    int oc = ow + it * 32;        // src col -> dst row offset
    ushort8v o;
#pragma unroll
    for (int j = 0; j < 8; j++) o[j] = f2bf(tile[u * 8 + j][oc]);
    *(ushort8v*)&dst[(size_t)(c0 + oc) * R + r0 + u * 8] = o;
  }
}

// ---------------- combine: out[t] += eout[pos0[t]] + eout[pos1[t]] ----------------
__global__ void combine_kernel(float* __restrict__ out,
                               const unsigned short* __restrict__ eout,
                               const int* __restrict__ pos) {
  int t = blockIdx.x;
  int d = threadIdx.x * 8;
  int p0 = pos[t * 2], p1 = pos[t * 2 + 1];
  float* o = out + (size_t)t * DM + d;
  const unsigned short* e0 = eout + (size_t)p0 * DM + d;
  const unsigned short* e1 = eout + (size_t)p1 * DM + d;
  float4 a = *(const float4*)(o);
  float4 b = *(const float4*)(o + 4);
  ushort4 u0a = *(const ushort4*)(e0), u0b = *(const ushort4*)(e0 + 4);
  ushort4 u1a = *(const ushort4*)(e1), u1b = *(const ushort4*)(e1 + 4);
  a.x += bf2f(u0a.x) + bf2f(u1a.x);
  a.y += bf2f(u0a.y) + bf2f(u1a.y);
  a.z += bf2f(u0a.z) + bf2f(u1a.z);
  a.w += bf2f(u0a.w) + bf2f(u1a.w);
  b.x += bf2f(u0b.x) + bf2f(u1b.x);
  b.y += bf2f(u0b.y) + bf2f(u1b.y);
  b.z += bf2f(u0b.z) + bf2f(u1b.z);
  b.w += bf2f(u0b.w) + bf2f(u1b.w);
  *(float4*)(o) = a;
  *(float4*)(o + 4) = b;
}

// ---------------- 128x128xBK64 bf16 MFMA GEMM, m97-canonical single buffer ----------------
// 256 threads = 4 waves (2x2 of 64x64 wave tiles). LDS 32KB, 4 blocks/CU
// (64 VGPR + 64 AGPR = 128 unified = the 4/CU cliff; no extra live regs).
// MODE 0 = sk (dense rows, gelu bf16 out)      MODE 1 = sv (dense, f32 out)
// MODE 2 = ek (perm-gathered, gelu bf16 out)   MODE 3 = ev (weighted bf16 out)
template<int MODE>
__device__ __forceinline__ void gemm_body(
    int id,
    const unsigned short* __restrict__ A,
    const unsigned short* __restrict__ BT,
    const float* __restrict__ bias,
    float* __restrict__ outF,
    unsigned short* __restrict__ outH,
    int Kd, int Nd,
    const int* __restrict__ perm,
    const float* __restrict__ permw,
    const int* __restrict__ tileE,
    const int* __restrict__ tileR,
    const int* __restrict__ nTiles) {
  __shared__ __align__(16) unsigned short As[128 * 64];
  __shared__ __align__(16) unsigned short Bs[128 * 64];

  int xcd = id & 7, q = id >> 3;
  int mt, ntile;
  if (MODE == 0) {              // band 8m, m-fastest
    mt = xcd * 8 + (q & 7);
    ntile = q >> 3;
  } else if (MODE == 1) {       // band 8m, n-fastest
    ntile = q & 7;
    mt = xcd * 8 + (q >> 3);
  } else if (MODE == 2) {       // band 17m, supertile 4m x 8n
    int n_in = q & 7, m_in = (q >> 3) & 3, ng = (q >> 5) & 3, mg = q >> 7;
    int mband = mg * 4 + m_in;
    if (mband >= BAND) return;
    mt = xcd * BAND + mband;
    ntile = ng * 8 + n_in;
  } else {                      // band 17m, n-fastest per m
    mt = xcd * BAND + (q >> 3);
    ntile = q & 7;
  }

  int n0 = ntile * 128;
  int prow0 = 0, m0 = 0;
  if (MODE >= 2) {
    if (mt >= *nTiles) return;
    int e = tileE[mt];
    prow0 = tileR[mt];
    BT += (size_t)e * Kd * Nd;
    bias += (size_t)e * Nd;
  } else {
    m0 = mt * 128;
  }

  int t = threadIdx.x;
  int rsub = t >> 3;               // 0..31: row within 32-row staging slab
  int gc = (t & 7) ^ (rsub & 7);   // swizzled global 16B-chunk index
  const unsigned short* aptr[4];
  const unsigned short* bptr[4];
#pragma unroll
  for (int p = 0; p < 4; p++) {
    int r = rsub + p * 32;
    size_t grow;
    if (MODE == 2)      grow = (size_t)perm[prow0 + r];
    else if (MODE == 3) grow = (size_t)(prow0 + r);
    else                grow = (size_t)(m0 + r);
    aptr[p] = A + grow * Kd + gc * 8;
    bptr[p] = BT + (size_t)(n0 + r) * Kd + gc * 8;
  }
  // wave-uniform LDS staging bases (lane*16 is added by HW)
  char* ldsA = (char*)As + (t & 192) * 16;
  char* ldsB = (char*)Bs + (t & 192) * 16;

  int lane = t & 63;
  int wv = t >> 6;
  int wm = (wv >> 1) * 64, wn = (wv & 1) * 64;
  int lr = lane & 15, lq = lane >> 4;
  int rx = lr & 7;                  // read-side row XOR key

  floatx4 acc[4][4];
#pragma unroll
  for (int i = 0; i < 4; i++)
#pragma unroll
    for (int j = 0; j < 4; j++) acc[i][j] = (floatx4){0.f, 0.f, 0.f, 0.f};

  for (int k0 = 0; k0 < Kd; k0 += 64) {
#pragma unroll
    for (int p = 0; p < 4; p++) {
      gload16(aptr[p] + k0, ldsA + p * 4096);
      gload16(bptr[p] + k0, ldsB + p * 4096);
    }
    __syncthreads();               // drains vmcnt(0): tile staged
#pragma unroll
    for (int kk = 0; kk < 2; kk++) {       // two 16x16x32 k-steps
      int ca = kk * 4 + lq;                // global chunk for this frag
      bhalf8 af[4], bf[4];
#pragma unroll
      for (int i = 0; i < 4; i++) {
        af[i] = *(const bhalf8*)&As[(wm + i * 16 + lr) * 64 + ((ca ^ rx) * 8)];
        bf[i] = *(const bhalf8*)&Bs[(wn + i * 16 + lr) * 64 + ((ca ^ rx) * 8)];
      }
#pragma unroll
      for (int mtile = 0; mtile < 4; mtile++)
#pragma unroll
        for (int ntl = 0; ntl < 4; ntl++)
          acc[mtile][ntl] = __builtin_amdgcn_mfma_f32_16x16x32_bf16(af[mtile], bf[ntl], acc[mtile][ntl], 0, 0, 0);
    }
    __syncthreads();               // protect buffer before next stage
  }

  // epilogue: D[row=(lane>>4)*4+reg][col=lane&15]
#pragma unroll
  for (int mtile = 0; mtile < 4; mtile++) {
#pragma unroll
    for (int ntl = 0; ntl < 4; ntl++) {
      int ncol = n0 + wn + ntl * 16 + lr;
      float bb = bias[ncol];
#pragma unroll
      for (int r = 0; r < 4; r++) {
        int mrow = wm + mtile * 16 + lq * 4 + r;    // local row 0..127
        float v = acc[mtile][ntl][r] + bb;
        if (MODE == 0) {
          outH[(size_t)(m0 + mrow) * Nd + ncol] = f2bf(gelu_tanh(v));
        } else if (MODE == 1) {
          outF[(size_t)(m0 + mrow) * Nd + ncol] = v;
        } else if (MODE == 2) {
          outH[(size_t)(prow0 + mrow) * Nd + ncol] = f2bf(gelu_tanh(v));
        } else {
          int prow = prow0 + mrow;
          float w = permw[prow];
          outH[(size_t)prow * Nd + ncol] = f2bf(w * v);   // weighted expert out
        }
      }
    }
  }
}

// ---------------- kernels ----------------
__global__ __launch_bounds__(256, 4) void gemm_expert_keys(
    const unsigned short* A, const unsigned short* BT, const float* bias,
    float* outF, unsigned short* outH, int Kd, int Nd,
    const int* perm, const float* permw, const int* tE, const int* tR, const int* nT) {
  gemm_body<2>(blockIdx.x, A, BT, bias, outF, outH, Kd, Nd, perm, permw, tE, tR, nT);
}
__global__ __launch_bounds__(256, 4) void gemm_shared_values(
    const unsigned short* A, const unsigned short* BT, const float* bias,
    float* outF, unsigned short* outH, int Kd, int Nd,
    const int* perm, const float* permw, const int* tE, const int* tR, const int* nT) {
  gemm_body<1>(blockIdx.x, A, BT, bias, outF, outH, Kd, Nd, perm, permw, tE, tR, nT);
}
// merged: ids [0,1088) = expert_values (long items, launch first);
//         ids [1088,3136) = shared_keys (short items, backfill the tail).
__global__ __launch_bounds__(256, 4) void gemm_ev_sk(
    const unsigned short* hid, const unsigned short* wtV, const float* values_b,
    unsigned short* eout,
    const unsigned short* xb, const unsigned short* wtK8, const float* sk_b,
    unsigned short* hidS,
    const int* perm, const float* permw, const int* tE, const int* tR, const int* nT) {
  int id = blockIdx.x;
  if (id < EV_BLOCKS) {
    gemm_body<3>(id, hid, wtV, values_b, nullptr, eout, HD, DM,
                 perm, permw, tE, tR, nT);
  } else {
    gemm_body<0>(id - EV_BLOCKS, xb, wtK8, sk_b, nullptr, hidS, DM, HD,
                 perm, permw, tE, tR, nT);
  }
}

extern "C" void kernel_launch(void* const* d_in, const int* in_sizes, int n_in,
                              void* d_out, int out_size, void* d_ws, size_t ws_size,
                              hipStream_t stream) {
  const float* x        = (const float*)d_in[0];
  const float* gate_w   = (const float*)d_in[1];
  const float* keys_w   = (const float*)d_in[2];
  const float* keys_b   = (const float*)d_in[3];
  const float* values_w = (const float*)d_in[4];
  const float* values_b = (const float*)d_in[5];
  const float* sk_w     = (const float*)d_in[6];
  const float* sk_b     = (const float*)d_in[7];
  const float* sv_w     = (const float*)d_in[8];
  const float* sv_b     = (const float*)d_in[9];
  float* out = (float*)d_out;

  char* p = (char*)d_ws;
  unsigned short* xb   = (unsigned short*)p; p += (size_t)N_TOK * DM * 2;              // 16 MB
  unsigned short* wt   = (unsigned short*)p; p += (size_t)(NE + 1) * DM * HD * 2;      // 75.5 MB (9 slots)
  unsigned short* hid  = (unsigned short*)p; p += (size_t)(PERM_CAP + N_TOK) * HD * 2; // 209.7 MB
  unsigned short* eout = (unsigned short*)p; p += (size_t)PERM_CAP * DM * 2;           // 35.7 MB
  int*   idxb   = (int*)p;   p += NKTOT * 4;
  float* wbuf   = (float*)p; p += NKTOT * 4;
  int*   perm   = (int*)p;   p += PERM_CAP * 4;
  float* permw  = (float*)p; p += PERM_CAP * 4;
  int*   pos    = (int*)p;   p += NKTOT * 4;
  int*   counts = (int*)p;   p += NE * 4;
  int*   fill   = (int*)p;   p += NE * 4;
  int*   poff   = (int*)p;   p += NE * 4;
  float* usage  = (float*)p; p += NE * 4;
  float* zsum   = (float*)p; p += 16;
  int*   tileE  = (int*)p;   p += MAX_TILES * 4;
  int*   tileR  = (int*)p;   p += MAX_TILES * 4;
  int*   nTiles = (int*)p;   p += 16;

  float* lossOut = out + (size_t)N_TOK * DM;
  unsigned short* wt8  = wt + (size_t)NE * DM * HD;        // slot 8
  unsigned short* hidS = hid + (size_t)PERM_CAP * HD;      // shared hidden rows

  // 1) init + convert + router
  init_kernel<<<(PERM_CAP + 255) / 256, 256, 0, stream>>>(perm, permw, usage, zsum, counts, fill);
  cvt_x_kernel<<<(N_TOK * DM / 4 + 255) / 256, 256, 0, stream>>>(x, xb);
  router_kernel<<<N_TOK / RTOK_BLK, 256, 0, stream>>>(x, gate_w, idxb, wbuf, usage, zsum, counts);
  scan_kernel<<<1, 64, 0, stream>>>(counts, poff, tileE, tileR, nTiles, usage, zsum, lossOut);
  scatter_kernel<<<NKTOT / 256, 256, 0, stream>>>(idxb, wbuf, poff, fill, perm, permw, pos);

  // 2) keys transposes: wt[0..7] = keys_w^T, wt[8] = sk_w^T
  transpose_cvt_kernel<<<dim3(DM / 64, HD / 64, NE), 256, 0, stream>>>(keys_w, wt, DM, HD);
  transpose_cvt_kernel<<<dim3(DM / 64, HD / 64, 1), 256, 0, stream>>>(sk_w, wt8, DM, HD);

  // 3) expert keys: hid[expert rows] = gelu(x[perm] @ Wk_e + b_e)
  gemm_expert_keys<<<5120, 256, 0, stream>>>(             // 8 xcd * 20(m pad) * 32 n
      xb, wt, keys_b, nullptr, hid, DM, HD, perm, permw, tileE, tileR, nTiles);

  // 4) values transpose (overwrites keys slots; ek done) then merged ev+sk:
  //    ev (long, first) reads hid+wt[0..7]; sk (short, backfill) reads xb+wt[8].
  transpose_cvt_kernel<<<dim3(HD / 64, DM / 64, NE), 256, 0, stream>>>(values_w, wt, HD, DM);
  gemm_ev_sk<<<EV_BLOCKS + 2048, 256, 0, stream>>>(
      hid, wt, values_b, eout, xb, wt8, sk_b, hidS,
      perm, permw, tileE, tileR, nTiles);

  // 5) shared values: out = hidS @ Wv_s + b (f32); wt[8] = sv_w^T (sk done)
  transpose_cvt_kernel<<<dim3(HD / 64, DM / 64, 1), 256, 0, stream>>>(sv_w, wt8, HD, DM);
  gemm_shared_values<<<512, 256, 0, stream>>>(            // 8 xcd * 8 m * 8 n
      hidS, wt8, sv_b, out, nullptr, HD, DM, perm, permw, tileE, tileR, nTiles);

  // 6) out += top-2 expert contributions
  combine_kernel<<<N_TOK, 128, 0, stream>>>(out, eout, pos);
}

// Round 11
// 886.845 us; speedup vs baseline: 1.0616x; 1.0616x over previous
//
#include <hip/hip_runtime.h>
#include <hip/hip_bf16.h>

// MoE top-2-of-8 FFN + shared expert + router losses, MI355X gfx950.
// R8: m97-canonical 128^2 single-buffer GEMM, 4 blocks/CU (926us best).
// R9-R13 lessons: 128-unified-reg / 32KB-LDS = the 4-blocks/CU cliff; per-CU
//     rate needs >=4-deep block TLP; tile-shape variants don't help; merges
//     only pay if they remove idle rounds WITHOUT dropping below the cliff.
// R14 post-mortem: merged ev+sk via TWO template instantiations -> compiler
//     allocated 2x32KB LDS (65536/block!) + VGPR 96 (union of live ranges)
//     -> 2 blocks/CU -> 312us (worse than 262 separate). Mechanism untested.
// R15: same backfill, ONE unified code path: single 32KB __shared__ pair,
//     block-uniform runtime selects (ev = id < 1088) for {A,B,bias,Kd,Nd,
//     rowbase,epilogue}. K-loop/staging instructions identical across both
//     branches -> VGPR ~64, LDS 32768, 4 blocks/CU restored. Backfill math:
//     busy = 1088*105 + 2048*26 ~ 168k slot-us / 1024 ~ 164us ideal.

#define N_TOK 8192
#define DM    1024
#define HD    4096
#define NE    8
#define NKTOT 16384            // N_TOK * 2
#define PERM_CAP 17408         // NKTOT + NE*128 (segment padding)
#define MAX_TILES 136          // sum ceil(T_e/128) <= NKTOT/128 + NE
#define BAND 17                // MAX_TILES / 8 xcds
#define EV_BLOCKS 1088         // 8 xcd * 17 m * 8 n
#define RTOK_BLK 16            // router tokens per block

typedef __attribute__((ext_vector_type(8))) short bhalf8;
typedef __attribute__((ext_vector_type(8))) unsigned short ushort8v;
typedef __attribute__((ext_vector_type(4))) float floatx4;

__device__ __forceinline__ unsigned short f2bf(float f) {
  union { float f; unsigned int u; } v; v.f = f;
  unsigned int u = v.u;
  return (unsigned short)((u + 0x7fffu + ((u >> 16) & 1u)) >> 16);  // RNE
}

__device__ __forceinline__ float bf2f(unsigned short h) {
  union { unsigned int u; float f; } v; v.u = ((unsigned int)h) << 16;
  return v.f;
}

__device__ __forceinline__ float gelu_tanh(float h) {
  // jax.nn.gelu default (approximate=True)
  float u = 0.7978845608028654f * (h + 0.044715f * h * h * h);
  float t = 1.0f - 2.0f / (1.0f + __expf(2.0f * u));   // tanh(u)
  return 0.5f * h * (1.0f + t);
}

// global -> LDS direct DMA, 16B/lane. LDS dest is wave-uniform base + lane*16.
__device__ __forceinline__ void gload16(const unsigned short* g, void* l) {
  __builtin_amdgcn_global_load_lds(
      (const __attribute__((address_space(1))) void*)g,
      (__attribute__((address_space(3))) void*)l, 16, 0, 0);
}

// ---------------- init (ws is poisoned 0xAA each call) ----------------
__global__ void init_kernel(int* perm, float* permw, float* usage, float* zsum,
                            int* counts, int* fill) {
  int i = blockIdx.x * 256 + threadIdx.x;
  if (i < PERM_CAP) { perm[i] = 0; permw[i] = 0.0f; }
  if (i < NE) { usage[i] = 0.0f; counts[i] = 0; fill[i] = 0; }
  if (i == 0) zsum[0] = 0.0f;
}

// ---------------- x fp32 -> bf16 ----------------
__global__ void cvt_x_kernel(const float* __restrict__ x, unsigned short* __restrict__ xb) {
  size_t i = (size_t)(blockIdx.x * 256 + threadIdx.x) * 4;
  float4 v = *(const float4*)(x + i);
  ushort4 o;
  o.x = f2bf(v.x); o.y = f2bf(v.y); o.z = f2bf(v.z); o.w = f2bf(v.w);
  *(ushort4*)(xb + i) = o;
}

// ---------------- router: logits, top-2 softmax, aux-loss partials ----------------
__global__ void router_kernel(const float* __restrict__ x, const float* __restrict__ gw,
                              int* __restrict__ idxb, float* __restrict__ wbuf,
                              float* __restrict__ usage, float* __restrict__ zsum,
                              int* __restrict__ counts) {
  __shared__ float s_use[NE];
  __shared__ int   s_cnt[NE];
  __shared__ float s_z;
  int t = threadIdx.x;
  if (t < NE) { s_use[t] = 0.0f; s_cnt[t] = 0; }
  if (t == 0) s_z = 0.0f;
  __syncthreads();

  int wave = t >> 6;
  int lane = t & 63;

  float luse[NE]; int lcnt[NE];
#pragma unroll
  for (int e = 0; e < NE; e++) { luse[e] = 0.0f; lcnt[e] = 0; }
  float lz = 0.0f;

#pragma unroll
  for (int i = 0; i < 4; i++) {
    int n = blockIdx.x * RTOK_BLK + wave * 4 + i;
    const float* xr = x + (size_t)n * DM;
    float acc[NE];
#pragma unroll
    for (int e = 0; e < NE; e++) acc[e] = 0.0f;
    for (int d = lane; d < DM; d += 64) {
      float xv = xr[d];
      const float* g = gw + (size_t)d * NE;
#pragma unroll
      for (int e = 0; e < NE; e++) acc[e] += xv * g[e];
    }
#pragma unroll
    for (int e = 0; e < NE; e++) {
#pragma unroll
      for (int off = 32; off > 0; off >>= 1) acc[e] += __shfl_xor(acc[e], off);
    }
    if (lane == 0) {
      float m1 = acc[0]; int i1 = 0;
#pragma unroll
      for (int e = 1; e < NE; e++) if (acc[e] > m1) { m1 = acc[e]; i1 = e; }
      float m2 = -3.0e38f; int i2 = 0;
#pragma unroll
      for (int e = 0; e < NE; e++) if (e != i1 && acc[e] > m2) { m2 = acc[e]; i2 = e; }
      float e1 = __expf(m2 - m1);
      float w1 = 1.0f / (1.0f + e1);
      float w2 = e1 / (1.0f + e1);
      float s = 0.0f;
#pragma unroll
      for (int e = 0; e < NE; e++) s += __expf(acc[e] - m1);
      float lse = m1 + __logf(s);
      idxb[n * 2 + 0] = i1; idxb[n * 2 + 1] = i2;
      wbuf[n * 2 + 0] = w1; wbuf[n * 2 + 1] = w2;
      luse[i1] += w1; luse[i2] += w2;
      lcnt[i1]++;     lcnt[i2]++;
      lz += lse * lse;
    }
  }

  if (lane == 0) {
#pragma unroll
    for (int e = 0; e < NE; e++) {
      atomicAdd(&s_use[e], luse[e]);
      atomicAdd(&s_cnt[e], lcnt[e]);
    }
    atomicAdd(&s_z, lz);
  }
  __syncthreads();
  if (t < NE) {
    atomicAdd(&usage[t], s_use[t]);
    atomicAdd(&counts[t], s_cnt[t]);
  }
  if (t == 0) atomicAdd(zsum, s_z);
}

// ---------------- scan: padded segment offsets, tile table, router loss ----------------
__global__ void scan_kernel(const int* __restrict__ counts, int* __restrict__ poff,
                            int* __restrict__ tileE, int* __restrict__ tileR,
                            int* __restrict__ nTiles,
                            const float* __restrict__ usage, const float* __restrict__ zsum,
                            float* __restrict__ lossOut) {
  if (threadIdx.x == 0 && blockIdx.x == 0) {
    int run = 0, nt = 0;
    for (int e = 0; e < NE; e++) {
      poff[e] = run;
      int t = (counts[e] + 127) >> 7;
      for (int i = 0; i < t; i++) { tileE[nt] = e; tileR[nt] = run + i * 128; nt++; }
      run += t << 7;
    }
    *nTiles = nt;
    float mean = 0.0f;
    for (int e = 0; e < NE; e++) mean += usage[e];
    mean *= (1.0f / NE);
    float var = 0.0f;
    for (int e = 0; e < NE; e++) { float d = usage[e] - mean; var += d * d; }
    var *= (1.0f / NE);
    float bal = sqrtf(var) / mean * 0.01f;
    float z = (zsum[0] / (float)N_TOK) * 0.001f;
    lossOut[0] = bal + z;
  }
}

// ---------------- scatter tokens into per-expert segments ----------------
__global__ void scatter_kernel(const int* __restrict__ idxb, const float* __restrict__ wbuf,
                               const int* __restrict__ poff, int* __restrict__ fill,
                               int* __restrict__ perm, float* __restrict__ permw,
                               int* __restrict__ pos) {
  __shared__ int lcnt[NE];
  __shared__ int lbase[NE];
  int t = threadIdx.x;
  if (t < NE) lcnt[t] = 0;
  __syncthreads();
  int i = blockIdx.x * 256 + t;          // grid sized exactly: i < NKTOT
  int e = idxb[i];
  int r = atomicAdd(&lcnt[e], 1);        // LDS rank within block
  __syncthreads();
  if (t < NE) lbase[t] = atomicAdd(&fill[t], lcnt[t]);
  __syncthreads();
  int p = poff[e] + lbase[e] + r;
  perm[p] = i >> 1;
  permw[p] = wbuf[i];
  pos[i] = p;
}

// ---------------- transpose+convert: src fp32 [R][C] -> dst bf16 [C][R], batched ----------------
__global__ void transpose_cvt_kernel(const float* __restrict__ src,
                                     unsigned short* __restrict__ dst, int R, int C) {
  __shared__ float tile[64][65];
  size_t bo = (size_t)blockIdx.z * R * C;
  src += bo; dst += bo;
  int r0 = blockIdx.x * 64, c0 = blockIdx.y * 64;
  int c = threadIdx.x & 63, r = threadIdx.x >> 6;
#pragma unroll
  for (int i = 0; i < 16; i++)
    tile[r + i * 4][c] = src[(size_t)(r0 + r + i * 4) * C + c0 + c];
  __syncthreads();
  int u = threadIdx.x & 7;        // dst 8-col group (src row group)
  int ow = threadIdx.x >> 3;      // 0..31: dst row offset base
#pragma unroll
  for (int it = 0; it < 2; it++) {
    int oc = ow + it * 32;        // src col -> dst row offset
    ushort8v o;
#pragma unroll
    for (int j = 0; j < 8; j++) o[j] = f2bf(tile[u * 8 + j][oc]);
    *(ushort8v*)&dst[(size_t)(c0 + oc) * R + r0 + u * 8] = o;
  }
}

// ---------------- combine: out[t] += eout[pos0[t]] + eout[pos1[t]] ----------------
__global__ void combine_kernel(float* __restrict__ out,
                               const unsigned short* __restrict__ eout,
                               const int* __restrict__ pos) {
  int t = blockIdx.x;
  int d = threadIdx.x * 8;
  int p0 = pos[t * 2], p1 = pos[t * 2 + 1];
  float* o = out + (size_t)t * DM + d;
  const unsigned short* e0 = eout + (size_t)p0 * DM + d;
  const unsigned short* e1 = eout + (size_t)p1 * DM + d;
  float4 a = *(const float4*)(o);
  float4 b = *(const float4*)(o + 4);
  ushort4 u0a = *(const ushort4*)(e0), u0b = *(const ushort4*)(e0 + 4);
  ushort4 u1a = *(const ushort4*)(e1), u1b = *(const ushort4*)(e1 + 4);
  a.x += bf2f(u0a.x) + bf2f(u1a.x);
  a.y += bf2f(u0a.y) + bf2f(u1a.y);
  a.z += bf2f(u0a.z) + bf2f(u1a.z);
  a.w += bf2f(u0a.w) + bf2f(u1a.w);
  b.x += bf2f(u0b.x) + bf2f(u1b.x);
  b.y += bf2f(u0b.y) + bf2f(u1b.y);
  b.z += bf2f(u0b.z) + bf2f(u1b.z);
  b.w += bf2f(u0b.w) + bf2f(u1b.w);
  *(float4*)(o) = a;
  *(float4*)(o + 4) = b;
}

// ---------------- 128x128xBK64 bf16 MFMA GEMM, m97-canonical single buffer ----------------
// 256 threads = 4 waves (2x2 of 64x64 wave tiles). LDS 32KB, 4 blocks/CU
// (64 VGPR + 64 AGPR = 128 unified = the 4/CU cliff; no extra live regs).
// MODE 1 = sv (dense rows, f32 out)   MODE 2 = ek (perm rows, gelu bf16 out)
template<int MODE>
__device__ __forceinline__ void gemm_body(
    int id,
    const unsigned short* __restrict__ A,
    const unsigned short* __restrict__ BT,
    const float* __restrict__ bias,
    float* __restrict__ outF,
    unsigned short* __restrict__ outH,
    int Kd, int Nd,
    const int* __restrict__ perm,
    const int* __restrict__ tileE,
    const int* __restrict__ tileR,
    const int* __restrict__ nTiles) {
  __shared__ __align__(16) unsigned short As[128 * 64];
  __shared__ __align__(16) unsigned short Bs[128 * 64];

  int xcd = id & 7, q = id >> 3;
  int mt, ntile;
  if (MODE == 1) {              // band 8m, n-fastest
    ntile = q & 7;
    mt = xcd * 8 + (q >> 3);
  } else {                      // band 17m, supertile 4m x 8n
    int n_in = q & 7, m_in = (q >> 3) & 3, ng = (q >> 5) & 3, mg = q >> 7;
    int mband = mg * 4 + m_in;
    if (mband >= BAND) return;
    mt = xcd * BAND + mband;
    ntile = ng * 8 + n_in;
  }

  int n0 = ntile * 128;
  int prow0 = 0, m0 = 0;
  if (MODE == 2) {
    if (mt >= *nTiles) return;
    int e = tileE[mt];
    prow0 = tileR[mt];
    BT += (size_t)e * Kd * Nd;
    bias += (size_t)e * Nd;
  } else {
    m0 = mt * 128;
  }

  int t = threadIdx.x;
  int rsub = t >> 3;               // 0..31: row within 32-row staging slab
  int gc = (t & 7) ^ (rsub & 7);   // swizzled global 16B-chunk index
  const unsigned short* aptr[4];
  const unsigned short* bptr[4];
#pragma unroll
  for (int p = 0; p < 4; p++) {
    int r = rsub + p * 32;
    size_t grow;
    if (MODE == 2) grow = (size_t)perm[prow0 + r];
    else           grow = (size_t)(m0 + r);
    aptr[p] = A + grow * Kd + gc * 8;
    bptr[p] = BT + (size_t)(n0 + r) * Kd + gc * 8;
  }
  char* ldsA = (char*)As + (t & 192) * 16;
  char* ldsB = (char*)Bs + (t & 192) * 16;

  int lane = t & 63;
  int wv = t >> 6;
  int wm = (wv >> 1) * 64, wn = (wv & 1) * 64;
  int lr = lane & 15, lq = lane >> 4;
  int rx = lr & 7;                  // read-side row XOR key

  floatx4 acc[4][4];
#pragma unroll
  for (int i = 0; i < 4; i++)
#pragma unroll
    for (int j = 0; j < 4; j++) acc[i][j] = (floatx4){0.f, 0.f, 0.f, 0.f};

  for (int k0 = 0; k0 < Kd; k0 += 64) {
#pragma unroll
    for (int p = 0; p < 4; p++) {
      gload16(aptr[p] + k0, ldsA + p * 4096);
      gload16(bptr[p] + k0, ldsB + p * 4096);
    }
    __syncthreads();               // drains vmcnt(0): tile staged
#pragma unroll
    for (int kk = 0; kk < 2; kk++) {       // two 16x16x32 k-steps
      int ca = kk * 4 + lq;                // global chunk for this frag
      bhalf8 af[4], bf[4];
#pragma unroll
      for (int i = 0; i < 4; i++) {
        af[i] = *(const bhalf8*)&As[(wm + i * 16 + lr) * 64 + ((ca ^ rx) * 8)];
        bf[i] = *(const bhalf8*)&Bs[(wn + i * 16 + lr) * 64 + ((ca ^ rx) * 8)];
      }
#pragma unroll
      for (int mtile = 0; mtile < 4; mtile++)
#pragma unroll
        for (int ntl = 0; ntl < 4; ntl++)
          acc[mtile][ntl] = __builtin_amdgcn_mfma_f32_16x16x32_bf16(af[mtile], bf[ntl], acc[mtile][ntl], 0, 0, 0);
    }
    __syncthreads();               // protect buffer before next stage
  }

  // epilogue: D[row=(lane>>4)*4+reg][col=lane&15]
#pragma unroll
  for (int mtile = 0; mtile < 4; mtile++) {
#pragma unroll
    for (int ntl = 0; ntl < 4; ntl++) {
      int ncol = n0 + wn + ntl * 16 + lr;
      float bb = bias[ncol];
#pragma unroll
      for (int r = 0; r < 4; r++) {
        int mrow = wm + mtile * 16 + lq * 4 + r;    // local row 0..127
        float v = acc[mtile][ntl][r] + bb;
        if (MODE == 1) {
          outF[(size_t)(m0 + mrow) * Nd + ncol] = v;
        } else {
          outH[(size_t)(prow0 + mrow) * Nd + ncol] = f2bf(gelu_tanh(v));
        }
      }
    }
  }
}

__global__ __launch_bounds__(256, 4) void gemm_expert_keys(
    const unsigned short* A, const unsigned short* BT, const float* bias,
    float* outF, unsigned short* outH, int Kd, int Nd,
    const int* perm, const int* tE, const int* tR, const int* nT) {
  gemm_body<2>(blockIdx.x, A, BT, bias, outF, outH, Kd, Nd, perm, tE, tR, nT);
}
__global__ __launch_bounds__(256, 4) void gemm_shared_values(
    const unsigned short* A, const unsigned short* BT, const float* bias,
    float* outF, unsigned short* outH, int Kd, int Nd,
    const int* perm, const int* tE, const int* tR, const int* nT) {
  gemm_body<1>(blockIdx.x, A, BT, bias, outF, outH, Kd, Nd, perm, tE, tR, nT);
}

// ---------------- merged ev+sk: ONE code path, runtime block-uniform selects ----------------
// ids [0,1088) = expert_values (K=4096 long items, launch first);
// ids [1088,3136) = shared_keys (K=1024 short items, backfill the tail).
// Both branches use direct row addressing (hid is already permuted), so the
// staging + K-loop is the same instruction stream; only scalar setup and the
// epilogue differ. Single 32KB __shared__ pair -> 4 blocks/CU.
__global__ __launch_bounds__(256, 4) void gemm_ev_sk(
    const unsigned short* __restrict__ hid, const unsigned short* __restrict__ wtV,
    const float* __restrict__ values_b, unsigned short* __restrict__ eout,
    const unsigned short* __restrict__ xb, const unsigned short* __restrict__ wtK8,
    const float* __restrict__ sk_b, unsigned short* __restrict__ hidS,
    const float* __restrict__ permw,
    const int* __restrict__ tileE, const int* __restrict__ tileR,
    const int* __restrict__ nTiles) {
  __shared__ __align__(16) unsigned short As[128 * 64];
  __shared__ __align__(16) unsigned short Bs[128 * 64];

  int id = blockIdx.x;
  bool is_ev = id < EV_BLOCKS;

  int Kd, rbase, n0;
  const unsigned short* A;
  const unsigned short* BT;
  const float* bias;
  if (is_ev) {                       // band 17m, n-fastest per m
    int xcd = id & 7, q = id >> 3;
    int mt = xcd * BAND + (q >> 3);
    if (mt >= *nTiles) return;
    int e = tileE[mt];
    rbase = tileR[mt];
    n0 = (q & 7) * 128;
    Kd = HD;
    A = hid;
    BT = wtV + (size_t)e * HD * DM;
    bias = values_b + (size_t)e * DM;
  } else {                           // sk: band 8m, m-fastest
    int id2 = id - EV_BLOCKS;
    int xcd = id2 & 7, q = id2 >> 3;
    int mt = xcd * 8 + (q & 7);
    rbase = mt * 128;
    n0 = (q >> 3) * 128;
    Kd = DM;
    A = xb;
    BT = wtK8;
    bias = sk_b;
  }

  int t = threadIdx.x;
  int rsub = t >> 3;               // 0..31: row within 32-row staging slab
  int gc = (t & 7) ^ (rsub & 7);   // swizzled global 16B-chunk index
  const unsigned short* aptr[4];
  const unsigned short* bptr[4];
#pragma unroll
  for (int p = 0; p < 4; p++) {
    int r = rsub + p * 32;
    aptr[p] = A + (size_t)(rbase + r) * Kd + gc * 8;
    bptr[p] = BT + (size_t)(n0 + r) * Kd + gc * 8;
  }
  char* ldsA = (char*)As + (t & 192) * 16;
  char* ldsB = (char*)Bs + (t & 192) * 16;

  int lane = t & 63;
  int wv = t >> 6;
  int wm = (wv >> 1) * 64, wn = (wv & 1) * 64;
  int lr = lane & 15, lq = lane >> 4;
  int rx = lr & 7;                  // read-side row XOR key

  floatx4 acc[4][4];
#pragma unroll
  for (int i = 0; i < 4; i++)
#pragma unroll
    for (int j = 0; j < 4; j++) acc[i][j] = (floatx4){0.f, 0.f, 0.f, 0.f};

  for (int k0 = 0; k0 < Kd; k0 += 64) {
#pragma unroll
    for (int p = 0; p < 4; p++) {
      gload16(aptr[p] + k0, ldsA + p * 4096);
      gload16(bptr[p] + k0, ldsB + p * 4096);
    }
    __syncthreads();
#pragma unroll
    for (int kk = 0; kk < 2; kk++) {
      int ca = kk * 4 + lq;
      bhalf8 af[4], bf[4];
#pragma unroll
      for (int i = 0; i < 4; i++) {
        af[i] = *(const bhalf8*)&As[(wm + i * 16 + lr) * 64 + ((ca ^ rx) * 8)];
        bf[i] = *(const bhalf8*)&Bs[(wn + i * 16 + lr) * 64 + ((ca ^ rx) * 8)];
      }
#pragma unroll
      for (int mtile = 0; mtile < 4; mtile++)
#pragma unroll
        for (int ntl = 0; ntl < 4; ntl++)
          acc[mtile][ntl] = __builtin_amdgcn_mfma_f32_16x16x32_bf16(af[mtile], bf[ntl], acc[mtile][ntl], 0, 0, 0);
    }
    __syncthreads();
  }

  // epilogue (block-uniform branch): ev -> weighted bf16 eout[prow*DM];
  // sk -> gelu bf16 hidS[(rbase+mrow)*HD]
  if (is_ev) {
#pragma unroll
    for (int mtile = 0; mtile < 4; mtile++) {
#pragma unroll
      for (int ntl = 0; ntl < 4; ntl++) {
        int ncol = n0 + wn + ntl * 16 + lr;
        float bb = bias[ncol];
#pragma unroll
        for (int r = 0; r < 4; r++) {
          int prow = rbase + wm + mtile * 16 + lq * 4 + r;
          float w = permw[prow];
          float v = acc[mtile][ntl][r] + bb;
          eout[(size_t)prow * DM + ncol] = f2bf(w * v);
        }
      }
    }
  } else {
#pragma unroll
    for (int mtile = 0; mtile < 4; mtile++) {
#pragma unroll
      for (int ntl = 0; ntl < 4; ntl++) {
        int ncol = n0 + wn + ntl * 16 + lr;
        float bb = bias[ncol];
#pragma unroll
        for (int r = 0; r < 4; r++) {
          int mrow = rbase + wm + mtile * 16 + lq * 4 + r;
          float v = acc[mtile][ntl][r] + bb;
          hidS[(size_t)mrow * HD + ncol] = f2bf(gelu_tanh(v));
        }
      }
    }
  }
}

extern "C" void kernel_launch(void* const* d_in, const int* in_sizes, int n_in,
                              void* d_out, int out_size, void* d_ws, size_t ws_size,
                              hipStream_t stream) {
  const float* x        = (const float*)d_in[0];
  const float* gate_w   = (const float*)d_in[1];
  const float* keys_w   = (const float*)d_in[2];
  const float* keys_b   = (const float*)d_in[3];
  const float* values_w = (const float*)d_in[4];
  const float* values_b = (const float*)d_in[5];
  const float* sk_w     = (const float*)d_in[6];
  const float* sk_b     = (const float*)d_in[7];
  const float* sv_w     = (const float*)d_in[8];
  const float* sv_b     = (const float*)d_in[9];
  float* out = (float*)d_out;

  char* p = (char*)d_ws;
  unsigned short* xb   = (unsigned short*)p; p += (size_t)N_TOK * DM * 2;              // 16 MB
  unsigned short* wt   = (unsigned short*)p; p += (size_t)(NE + 1) * DM * HD * 2;      // 75.5 MB (9 slots)
  unsigned short* hid  = (unsigned short*)p; p += (size_t)(PERM_CAP + N_TOK) * HD * 2; // 209.7 MB
  unsigned short* eout = (unsigned short*)p; p += (size_t)PERM_CAP * DM * 2;           // 35.7 MB
  int*   idxb   = (int*)p;   p += NKTOT * 4;
  float* wbuf   = (float*)p; p += NKTOT * 4;
  int*   perm   = (int*)p;   p += PERM_CAP * 4;
  float* permw  = (float*)p; p += PERM_CAP * 4;
  int*   pos    = (int*)p;   p += NKTOT * 4;
  int*   counts = (int*)p;   p += NE * 4;
  int*   fill   = (int*)p;   p += NE * 4;
  int*   poff   = (int*)p;   p += NE * 4;
  float* usage  = (float*)p; p += NE * 4;
  float* zsum   = (float*)p; p += 16;
  int*   tileE  = (int*)p;   p += MAX_TILES * 4;
  int*   tileR  = (int*)p;   p += MAX_TILES * 4;
  int*   nTiles = (int*)p;   p += 16;

  float* lossOut = out + (size_t)N_TOK * DM;
  unsigned short* wt8  = wt + (size_t)NE * DM * HD;        // slot 8
  unsigned short* hidS = hid + (size_t)PERM_CAP * HD;      // shared hidden rows

  // 1) init + convert + router
  init_kernel<<<(PERM_CAP + 255) / 256, 256, 0, stream>>>(perm, permw, usage, zsum, counts, fill);
  cvt_x_kernel<<<(N_TOK * DM / 4 + 255) / 256, 256, 0, stream>>>(x, xb);
  router_kernel<<<N_TOK / RTOK_BLK, 256, 0, stream>>>(x, gate_w, idxb, wbuf, usage, zsum, counts);
  scan_kernel<<<1, 64, 0, stream>>>(counts, poff, tileE, tileR, nTiles, usage, zsum, lossOut);
  scatter_kernel<<<NKTOT / 256, 256, 0, stream>>>(idxb, wbuf, poff, fill, perm, permw, pos);

  // 2) keys transposes: wt[0..7] = keys_w^T, wt[8] = sk_w^T
  transpose_cvt_kernel<<<dim3(DM / 64, HD / 64, NE), 256, 0, stream>>>(keys_w, wt, DM, HD);
  transpose_cvt_kernel<<<dim3(DM / 64, HD / 64, 1), 256, 0, stream>>>(sk_w, wt8, DM, HD);

  // 3) expert keys: hid[expert rows] = gelu(x[perm] @ Wk_e + b_e)
  gemm_expert_keys<<<5120, 256, 0, stream>>>(             // 8 xcd * 20(m pad) * 32 n
      xb, wt, keys_b, nullptr, hid, DM, HD, perm, tileE, tileR, nTiles);

  // 4) values transpose (overwrites keys slots; ek done), then merged ev+sk
  transpose_cvt_kernel<<<dim3(HD / 64, DM / 64, NE), 256, 0, stream>>>(values_w, wt, HD, DM);
  gemm_ev_sk<<<EV_BLOCKS + 2048, 256, 0, stream>>>(
      hid, wt, values_b, eout, xb, wt8, sk_b, hidS,
      permw, tileE, tileR, nTiles);

  // 5) shared values: out = hidS @ Wv_s + b (f32); wt[8] = sv_w^T (sk done)
  transpose_cvt_kernel<<<dim3(HD / 64, DM / 64, 1), 256, 0, stream>>>(sv_w, wt8, HD, DM);
  gemm_shared_values<<<512, 256, 0, stream>>>(            // 8 xcd * 8 m * 8 n
      hidS, wt8, sv_b, out, nullptr, HD, DM, perm, tileE, tileR, nTiles);

  // 6) out += top-2 expert contributions
  combine_kernel<<<N_TOK, 128, 0, stream>>>(out, eout, pos);
}